// Round 3
// baseline (511.499 us; speedup 1.0000x reference)
//
#include <hip/hip_runtime.h>
#include <hip/hip_bf16.h>

#define DH 32
#define BN 64        // nodes per block in node_proj
#define GN 8         // nodes per 32-lane group in node_proj
#define BSZ 256      // nodes per bucket  (BSZ*32*4 = 32 KB LDS agg slice)
#define NBP 512      // padded bucket count (N <= 131072 => B <= 512)
#define SCAT_E 4096  // edges per scatter/precount block
#define SCAT_P (2 * SCAT_E)

// ---------------------------------------------------------------------------
__global__ __launch_bounds__(256) void zero_counts(int* __restrict__ gtotal) {
    int i = blockIdx.x * 256 + threadIdx.x;
    if (i < NBP) gtotal[i] = 0;
}

// ---------------------------------------------------------------------------
// Per-bucket endpoint histogram.
// ---------------------------------------------------------------------------
__global__ __launch_bounds__(256) void precount(
    const int* __restrict__ src, const int* __restrict__ dst,
    int* __restrict__ gtotal, int E)
{
    __shared__ int hist[NBP];
    const int tid = threadIdx.x;
    for (int i = tid; i < NBP; i += 256) hist[i] = 0;
    __syncthreads();
    const int e0 = blockIdx.x * SCAT_E;
    const int eend = min(e0 + SCAT_E, E);
    for (int e = e0 + tid; e < eend; e += 256) {
        atomicAdd(&hist[src[e] >> 8], 1);
        atomicAdd(&hist[dst[e] >> 8], 1);
    }
    __syncthreads();
    for (int i = tid; i < NBP; i += 256)
        if (hist[i] > 0) atomicAdd(&gtotal[i], hist[i]);
}

// ---------------------------------------------------------------------------
// Exclusive scan of gtotal[0..NBP) -> gbase; gcursor = gbase. One block.
// ---------------------------------------------------------------------------
__global__ __launch_bounds__(256) void scan_buckets(
    const int* __restrict__ gtotal, int* __restrict__ gbase,
    int* __restrict__ gcursor)
{
    __shared__ int ss[256];
    const int t = threadIdx.x;
    int a = gtotal[2 * t], b = gtotal[2 * t + 1];
    int tsum = a + b;
    ss[t] = tsum;
    __syncthreads();
    for (int off = 1; off < 256; off <<= 1) {
        int y = (t >= off) ? ss[t - off] : 0;
        __syncthreads();
        ss[t] += y;
        __syncthreads();
    }
    int excl = ss[t] - tsum;
    gbase[2 * t] = excl;           gcursor[2 * t] = excl;
    gbase[2 * t + 1] = excl + a;   gcursor[2 * t + 1] = excl + a;
}

// ---------------------------------------------------------------------------
// Bucket-granular scatter: block-local sort by bucket in LDS, then coalesced
// run writes with one global cursor atomic per (block,bucket).
// pair code: (v & 255) << 17 | nbr   (requires N <= 131072)
// ---------------------------------------------------------------------------
__global__ __launch_bounds__(256) void bucket_scatter(
    const int* __restrict__ src, const int* __restrict__ dst,
    int* __restrict__ gcursor, unsigned* __restrict__ pairs_g,
    int E, int B)
{
    __shared__ unsigned s_code[SCAT_P];        // 32 KB
    __shared__ unsigned short s_bkt[SCAT_P];   // 16 KB
    __shared__ int hist[NBP], lbase[NBP], cur[NBP], gbL[NBP];  // 8 KB
    __shared__ int ss[256];

    const int tid = threadIdx.x;
    const int e0 = blockIdx.x * SCAT_E;
    const int eend = min(e0 + SCAT_E, E);
    const int np = 2 * (eend - e0);

    for (int i = tid; i < NBP; i += 256) hist[i] = 0;
    __syncthreads();

    // load up to 16 edges/thread into regs (static indexing only)
    int es[16], dr[16];
#pragma unroll
    for (int j = 0; j < 16; ++j) {
        int e = e0 + tid + j * 256;
        bool ok = (e < eend);
        es[j] = ok ? src[e] : -1;
        dr[j] = ok ? dst[e] : -1;
    }
#pragma unroll
    for (int j = 0; j < 16; ++j) {
        if (es[j] >= 0) {
            atomicAdd(&hist[es[j] >> 8], 1);
            atomicAdd(&hist[dr[j] >> 8], 1);
        }
    }
    __syncthreads();

    // exclusive scan over NBP=512 (2 elements per thread)
    {
        int a = hist[2 * tid], b = hist[2 * tid + 1];
        int tsum = a + b;
        ss[tid] = tsum;
        __syncthreads();
        for (int off = 1; off < 256; off <<= 1) {
            int y = (tid >= off) ? ss[tid - off] : 0;
            __syncthreads();
            ss[tid] += y;
            __syncthreads();
        }
        int excl = ss[tid] - tsum;
        lbase[2 * tid] = excl;         cur[2 * tid] = excl;
        lbase[2 * tid + 1] = excl + a; cur[2 * tid + 1] = excl + a;
    }
    __syncthreads();

    // rank + reorder into LDS
#pragma unroll
    for (int j = 0; j < 16; ++j) {
        if (es[j] >= 0) {
            int s = es[j], d = dr[j];
            int bs = s >> 8, bd = d >> 8;
            unsigned cs = ((unsigned)(s & 255) << 17) | (unsigned)d;
            unsigned cd = ((unsigned)(d & 255) << 17) | (unsigned)s;
            int p1 = atomicAdd(&cur[bs], 1);
            s_code[p1] = cs; s_bkt[p1] = (unsigned short)bs;
            int p2 = atomicAdd(&cur[bd], 1);
            s_code[p2] = cd; s_bkt[p2] = (unsigned short)bd;
        }
    }
    __syncthreads();

    // allocate global run per bucket
    for (int b = tid; b < B; b += 256) {
        int c = hist[b];
        if (c > 0) {
            int gw = atomicAdd(&gcursor[b], c);
            gbL[b] = gw - lbase[b];
        }
    }
    __syncthreads();

    // coalesced run writes
    for (int i = tid; i < np; i += 256) {
        int b = s_bkt[i];
        pairs_g[gbL[b] + i] = s_code[i];
    }
}

// ---------------------------------------------------------------------------
// h = feat @ W_in + b_in ; u = sigmoid(h @ W_nbr + b2)
// ---------------------------------------------------------------------------
__global__ __launch_bounds__(256) void node_proj(
    const float* __restrict__ feat,
    const float* __restrict__ W_in, const float* __restrict__ b_in,
    const float* __restrict__ W_nbr, const float* __restrict__ b_nbr,
    const float* __restrict__ b_n1,
    float* __restrict__ h, float* __restrict__ u, int N)
{
    __shared__ float sfeat[BN * 128];
    __shared__ float sWt_in[32 * 132];
    __shared__ float sWt_nbr[32 * 36];
    __shared__ float sh[BN * 32];
    __shared__ float sb_in[32], sb2[32];

    const int tid = threadIdx.x;
    const int base = blockIdx.x * BN;

    for (int i = tid; i < 128 * 32; i += 256) {
        int k = i >> 5, c = i & 31;
        sWt_in[c * 132 + k] = W_in[i];
    }
    for (int i = tid; i < 32 * 32; i += 256) {
        int k = i >> 5, c = i & 31;
        sWt_nbr[c * 36 + k] = W_nbr[i];
    }
    if (tid < 32) { sb_in[tid] = b_in[tid]; sb2[tid] = b_nbr[tid] + b_n1[tid]; }

    for (int i = tid; i < BN * 128 / 4; i += 256) {
        int row = i >> 5;
        int node = base + row;
        float4 v = make_float4(0.f, 0.f, 0.f, 0.f);
        if (node < N) v = *(const float4*)&feat[(size_t)node * 128 + (size_t)(i & 31) * 4];
        *(float4*)&sfeat[(size_t)i * 4] = v;
    }
    __syncthreads();

    const int g = tid >> 5, c = tid & 31;

    float acc[GN];
#pragma unroll
    for (int m = 0; m < GN; ++m) acc[m] = sb_in[c];

    const float* wcol = &sWt_in[c * 132];
    for (int kk = 0; kk < 128; kk += 4) {
        float4 w = *(const float4*)&wcol[kk];
#pragma unroll
        for (int m = 0; m < GN; ++m) {
            float4 f = *(const float4*)&sfeat[(g * GN + m) * 128 + kk];
            acc[m] += f.x * w.x + f.y * w.y + f.z * w.z + f.w * w.w;
        }
    }

#pragma unroll
    for (int m = 0; m < GN; ++m) {
        int node = base + g * GN + m;
        sh[(g * GN + m) * 32 + c] = acc[m];
        if (node < N) h[(size_t)node * 32 + c] = acc[m];
    }
    __syncthreads();

    float acc2[GN];
#pragma unroll
    for (int m = 0; m < GN; ++m) acc2[m] = sb2[c];

    const float* wcol2 = &sWt_nbr[c * 36];
    for (int kk = 0; kk < 32; kk += 4) {
        float4 w = *(const float4*)&wcol2[kk];
#pragma unroll
        for (int m = 0; m < GN; ++m) {
            float4 hf = *(const float4*)&sh[(g * GN + m) * 32 + kk];
            acc2[m] += hf.x * w.x + hf.y * w.y + hf.z * w.z + hf.w * w.w;
        }
    }

#pragma unroll
    for (int m = 0; m < GN; ++m) {
        int node = base + g * GN + m;
        if (node < N) {
            float s = 1.0f / (1.0f + __expf(-acc2[m]));
            u[(size_t)node * 32 + c] = s;
        }
    }
}

// ---------------------------------------------------------------------------
// Per-bucket segment max in LDS. Block b owns nodes [b*BSZ, b*BSZ+BSZ).
// 32-lane group per pair: lane = channel; LDS atomicMax is bank-conflict-free.
// Applies deg>1 mask on the coalesced write-out.
// ---------------------------------------------------------------------------
__global__ __launch_bounds__(256) void bucket_max(
    const unsigned* __restrict__ pairs_g, const int* __restrict__ gbase,
    const int* __restrict__ gtotal, const float* __restrict__ u,
    float* __restrict__ agg, int N)
{
    __shared__ unsigned aggL[BSZ * 32];   // 32 KB
    __shared__ int degL[BSZ];

    const int tid = threadIdx.x;
    const int b = blockIdx.x;
    const int v0 = b * BSZ;

    for (int i = tid; i < BSZ * 32; i += 256) aggL[i] = 0u;
    for (int i = tid; i < BSZ; i += 256) degL[i] = 0;
    __syncthreads();

    const int start = gbase[b], cnt = gtotal[b];
    const int g = tid >> 5, c = tid & 31;
    const int end = start + cnt;
    for (int p = start + g; p < end; p += 8) {
        unsigned code = pairs_g[p];
        int nb = code & 0x1FFFF;
        int vl = code >> 17;
        float x = u[(size_t)nb * DH + c];
        atomicMax(&aggL[vl * 32 + c], __float_as_uint(x));
        if (c == 0) atomicAdd(&degL[vl], 1);
    }
    __syncthreads();

    for (int i = tid; i < BSZ * 32; i += 256) {
        int vl = i >> 5;
        int v = v0 + vl;
        if (v < N) {
            float val = (degL[vl] > 1) ? __uint_as_float(aggL[i]) : 0.f;
            agg[(size_t)v0 * 32 + i] = val;
        }
    }
}

// ---------------------------------------------------------------------------
// out = concat(h, agg) @ W_ffnn + b_ffnn   (mask pre-applied in bucket_max)
// ---------------------------------------------------------------------------
__global__ __launch_bounds__(256) void finalize(
    const float* __restrict__ h, const float* __restrict__ agg,
    const float* __restrict__ W_ffnn, const float* __restrict__ b_ffnn,
    float* __restrict__ out, int N)
{
    __shared__ float sWt[32 * 68];
    __shared__ float sx[8][68];
    __shared__ float sb[32];

    const int tid = threadIdx.x;
    for (int i = tid; i < 64 * 32; i += 256) {
        int k = i >> 5, c = i & 31;
        sWt[c * 68 + k] = W_ffnn[i];
    }
    if (tid < 32) sb[tid] = b_ffnn[tid];

    const int g = tid >> 5, c = tid & 31;
    const int node = blockIdx.x * 8 + g;

    float hv = 0.f, av = 0.f;
    if (node < N) {
        hv = h[(size_t)node * DH + c];
        av = agg[(size_t)node * DH + c];
    }
    sx[g][c] = hv;
    sx[g][32 + c] = av;
    __syncthreads();

    float acc = sb[c];
    const float* wcol = &sWt[c * 68];
#pragma unroll
    for (int kk = 0; kk < 64; kk += 4) {
        float4 w = *(const float4*)&wcol[kk];
        float4 x = *(const float4*)&sx[g][kk];
        acc += x.x * w.x + x.y * w.y + x.z * w.z + x.w * w.w;
    }
    if (node < N) out[(size_t)node * DH + c] = acc;
}

// ---------------------------------------------------------------------------
extern "C" void kernel_launch(void* const* d_in, const int* in_sizes, int n_in,
                              void* d_out, int out_size, void* d_ws, size_t ws_size,
                              hipStream_t stream)
{
    const float* feat   = (const float*)d_in[0];
    const int*   src    = (const int*)d_in[1];
    const int*   dst    = (const int*)d_in[2];
    const float* W_in   = (const float*)d_in[3];
    const float* b_in   = (const float*)d_in[4];
    const float* W_nbr  = (const float*)d_in[5];
    const float* b_nbr  = (const float*)d_in[6];
    const float* b_n1   = (const float*)d_in[7];
    const float* W_ffnn = (const float*)d_in[8];
    const float* b_ffnn = (const float*)d_in[9];
    float* out = (float*)d_out;

    const int N = in_sizes[0] / 128;   // 100000 (N <= 131072 required by packing)
    const int E = in_sizes[1];
    const int B = (N + BSZ - 1) / BSZ; // 391 buckets (<= NBP)

    // u aliases d_out (consumed by bucket_max before finalize overwrites out)
    float* u = out;
    float* h       = (float*)d_ws;                  // N*32 f32
    float* agg     = h + (size_t)N * DH;            // N*32 f32
    int*   gtotal  = (int*)(agg + (size_t)N * DH);  // NBP
    int*   gbase   = gtotal + NBP;                  // NBP
    int*   gcursor = gbase + NBP;                   // NBP
    unsigned* pairs_g = (unsigned*)(gcursor + NBP); // 2E u32

    const int egrid = (E + SCAT_E - 1) / SCAT_E;

    zero_counts<<<(NBP + 255) / 256, 256, 0, stream>>>(gtotal);
    precount<<<egrid, 256, 0, stream>>>(src, dst, gtotal, E);
    scan_buckets<<<1, 256, 0, stream>>>(gtotal, gbase, gcursor);
    bucket_scatter<<<egrid, 256, 0, stream>>>(src, dst, gcursor, pairs_g, E, B);
    node_proj<<<(N + BN - 1) / BN, 256, 0, stream>>>(feat, W_in, b_in, W_nbr, b_nbr,
                                                     b_n1, h, u, N);
    bucket_max<<<B, 256, 0, stream>>>(pairs_g, gbase, gtotal, u, agg, N);
    finalize<<<(N + 7) / 8, 256, 0, stream>>>(h, agg, W_ffnn, b_ffnn, out, N);
}

// Round 4
// 248.417 us; speedup vs baseline: 2.0590x; 2.0590x over previous
//
#include <hip/hip_runtime.h>
#include <hip/hip_bf16.h>

#define DH 32
#define BN 64        // nodes per block in node_proj
#define GN 8         // nodes per 32-lane group in node_proj
#define BSZ 256      // nodes per bucket
#define NBP 512      // padded bucket count (N <= 131072 => B <= 512)
#define SCAT_E 4096  // edges per scatter/precount block
#define SCAT_P (2 * SCAT_E)
#define CPG 8        // channels per sub-block in bucket_max
#define NSPLIT 4     // 32 / CPG sub-blocks per bucket

// ---------------------------------------------------------------------------
__global__ __launch_bounds__(256) void zero_counts(int* __restrict__ gtotal) {
    int i = blockIdx.x * 256 + threadIdx.x;
    if (i < NBP) gtotal[i] = 0;
}

// ---------------------------------------------------------------------------
// Per-bucket endpoint histogram.
// ---------------------------------------------------------------------------
__global__ __launch_bounds__(256) void precount(
    const int* __restrict__ src, const int* __restrict__ dst,
    int* __restrict__ gtotal, int E)
{
    __shared__ int hist[NBP];
    const int tid = threadIdx.x;
    for (int i = tid; i < NBP; i += 256) hist[i] = 0;
    __syncthreads();
    const int e0 = blockIdx.x * SCAT_E;
    const int eend = min(e0 + SCAT_E, E);
    for (int e = e0 + tid; e < eend; e += 256) {
        atomicAdd(&hist[src[e] >> 8], 1);
        atomicAdd(&hist[dst[e] >> 8], 1);
    }
    __syncthreads();
    for (int i = tid; i < NBP; i += 256)
        if (hist[i] > 0) atomicAdd(&gtotal[i], hist[i]);
}

// ---------------------------------------------------------------------------
// Exclusive scan of gtotal[0..NBP) -> gbase; gcursor = gbase. One block.
// ---------------------------------------------------------------------------
__global__ __launch_bounds__(256) void scan_buckets(
    const int* __restrict__ gtotal, int* __restrict__ gbase,
    int* __restrict__ gcursor)
{
    __shared__ int ss[256];
    const int t = threadIdx.x;
    int a = gtotal[2 * t], b = gtotal[2 * t + 1];
    int tsum = a + b;
    ss[t] = tsum;
    __syncthreads();
    for (int off = 1; off < 256; off <<= 1) {
        int y = (t >= off) ? ss[t - off] : 0;
        __syncthreads();
        ss[t] += y;
        __syncthreads();
    }
    int excl = ss[t] - tsum;
    gbase[2 * t] = excl;           gcursor[2 * t] = excl;
    gbase[2 * t + 1] = excl + a;   gcursor[2 * t + 1] = excl + a;
}

// ---------------------------------------------------------------------------
// Bucket-granular scatter: block-local sort by bucket in LDS, then coalesced
// run writes with one global cursor atomic per (block,bucket).
// pair code: (v & 255) << 17 | nbr   (requires N <= 131072)
// ---------------------------------------------------------------------------
__global__ __launch_bounds__(256) void bucket_scatter(
    const int* __restrict__ src, const int* __restrict__ dst,
    int* __restrict__ gcursor, unsigned* __restrict__ pairs_g,
    int E, int B)
{
    __shared__ unsigned s_code[SCAT_P];        // 32 KB
    __shared__ unsigned short s_bkt[SCAT_P];   // 16 KB
    __shared__ int hist[NBP], lbase[NBP], cur[NBP], gbL[NBP];  // 8 KB
    __shared__ int ss[256];

    const int tid = threadIdx.x;
    const int e0 = blockIdx.x * SCAT_E;
    const int eend = min(e0 + SCAT_E, E);
    const int np = 2 * (eend - e0);

    for (int i = tid; i < NBP; i += 256) hist[i] = 0;
    __syncthreads();

    // load up to 16 edges/thread into regs (static indexing only)
    int es[16], dr[16];
#pragma unroll
    for (int j = 0; j < 16; ++j) {
        int e = e0 + tid + j * 256;
        bool ok = (e < eend);
        es[j] = ok ? src[e] : -1;
        dr[j] = ok ? dst[e] : -1;
    }
#pragma unroll
    for (int j = 0; j < 16; ++j) {
        if (es[j] >= 0) {
            atomicAdd(&hist[es[j] >> 8], 1);
            atomicAdd(&hist[dr[j] >> 8], 1);
        }
    }
    __syncthreads();

    // exclusive scan over NBP=512 (2 elements per thread)
    {
        int a = hist[2 * tid], b = hist[2 * tid + 1];
        int tsum = a + b;
        ss[tid] = tsum;
        __syncthreads();
        for (int off = 1; off < 256; off <<= 1) {
            int y = (tid >= off) ? ss[tid - off] : 0;
            __syncthreads();
            ss[tid] += y;
            __syncthreads();
        }
        int excl = ss[tid] - tsum;
        lbase[2 * tid] = excl;         cur[2 * tid] = excl;
        lbase[2 * tid + 1] = excl + a; cur[2 * tid + 1] = excl + a;
    }
    __syncthreads();

    // rank + reorder into LDS
#pragma unroll
    for (int j = 0; j < 16; ++j) {
        if (es[j] >= 0) {
            int s = es[j], d = dr[j];
            int bs = s >> 8, bd = d >> 8;
            unsigned cs = ((unsigned)(s & 255) << 17) | (unsigned)d;
            unsigned cd = ((unsigned)(d & 255) << 17) | (unsigned)s;
            int p1 = atomicAdd(&cur[bs], 1);
            s_code[p1] = cs; s_bkt[p1] = (unsigned short)bs;
            int p2 = atomicAdd(&cur[bd], 1);
            s_code[p2] = cd; s_bkt[p2] = (unsigned short)bd;
        }
    }
    __syncthreads();

    // allocate global run per bucket
    for (int b = tid; b < B; b += 256) {
        int c = hist[b];
        if (c > 0) {
            int gw = atomicAdd(&gcursor[b], c);
            gbL[b] = gw - lbase[b];
        }
    }
    __syncthreads();

    // coalesced run writes
    for (int i = tid; i < np; i += 256) {
        int b = s_bkt[i];
        pairs_g[gbL[b] + i] = s_code[i];
    }
}

// ---------------------------------------------------------------------------
// h = feat @ W_in + b_in ; u = sigmoid(h @ W_nbr + b2)
// ---------------------------------------------------------------------------
__global__ __launch_bounds__(256) void node_proj(
    const float* __restrict__ feat,
    const float* __restrict__ W_in, const float* __restrict__ b_in,
    const float* __restrict__ W_nbr, const float* __restrict__ b_nbr,
    const float* __restrict__ b_n1,
    float* __restrict__ h, float* __restrict__ u, int N)
{
    __shared__ float sfeat[BN * 128];
    __shared__ float sWt_in[32 * 132];
    __shared__ float sWt_nbr[32 * 36];
    __shared__ float sh[BN * 32];
    __shared__ float sb_in[32], sb2[32];

    const int tid = threadIdx.x;
    const int base = blockIdx.x * BN;

    for (int i = tid; i < 128 * 32; i += 256) {
        int k = i >> 5, c = i & 31;
        sWt_in[c * 132 + k] = W_in[i];
    }
    for (int i = tid; i < 32 * 32; i += 256) {
        int k = i >> 5, c = i & 31;
        sWt_nbr[c * 36 + k] = W_nbr[i];
    }
    if (tid < 32) { sb_in[tid] = b_in[tid]; sb2[tid] = b_nbr[tid] + b_n1[tid]; }

    for (int i = tid; i < BN * 128 / 4; i += 256) {
        int row = i >> 5;
        int node = base + row;
        float4 v = make_float4(0.f, 0.f, 0.f, 0.f);
        if (node < N) v = *(const float4*)&feat[(size_t)node * 128 + (size_t)(i & 31) * 4];
        *(float4*)&sfeat[(size_t)i * 4] = v;
    }
    __syncthreads();

    const int g = tid >> 5, c = tid & 31;

    float acc[GN];
#pragma unroll
    for (int m = 0; m < GN; ++m) acc[m] = sb_in[c];

    const float* wcol = &sWt_in[c * 132];
    for (int kk = 0; kk < 128; kk += 4) {
        float4 w = *(const float4*)&wcol[kk];
#pragma unroll
        for (int m = 0; m < GN; ++m) {
            float4 f = *(const float4*)&sfeat[(g * GN + m) * 128 + kk];
            acc[m] += f.x * w.x + f.y * w.y + f.z * w.z + f.w * w.w;
        }
    }

#pragma unroll
    for (int m = 0; m < GN; ++m) {
        int node = base + g * GN + m;
        sh[(g * GN + m) * 32 + c] = acc[m];
        if (node < N) h[(size_t)node * 32 + c] = acc[m];
    }
    __syncthreads();

    float acc2[GN];
#pragma unroll
    for (int m = 0; m < GN; ++m) acc2[m] = sb2[c];

    const float* wcol2 = &sWt_nbr[c * 36];
    for (int kk = 0; kk < 32; kk += 4) {
        float4 w = *(const float4*)&wcol2[kk];
#pragma unroll
        for (int m = 0; m < GN; ++m) {
            float4 hf = *(const float4*)&sh[(g * GN + m) * 32 + kk];
            acc2[m] += hf.x * w.x + hf.y * w.y + hf.z * w.z + hf.w * w.w;
        }
    }

#pragma unroll
    for (int m = 0; m < GN; ++m) {
        int node = base + g * GN + m;
        if (node < N) {
            float s = 1.0f / (1.0f + __expf(-acc2[m]));
            u[(size_t)node * 32 + c] = s;
        }
    }
}

// ---------------------------------------------------------------------------
// Per-bucket segment max in LDS, split 4 ways by channel (gridDim.y = NSPLIT;
// sub-block q owns channels [8q, 8q+8) of all BSZ nodes — disjoint, no merge).
// 8-lane group per pair; pair loop unrolled 4x for MLP (clamped duplicate
// gathers are harmless for max; deg increments are guarded).
// ---------------------------------------------------------------------------
__global__ __launch_bounds__(256) void bucket_max(
    const unsigned* __restrict__ pairs_g, const int* __restrict__ gbase,
    const int* __restrict__ gtotal, const float* __restrict__ u,
    float* __restrict__ agg, int N)
{
    __shared__ unsigned aggL[BSZ * CPG];   // 8 KB
    __shared__ int degL[BSZ];              // 1 KB

    const int tid = threadIdx.x;
    const int b = blockIdx.x;
    const int c0 = blockIdx.y * CPG;
    const int v0 = b * BSZ;

    for (int i = tid; i < BSZ * CPG; i += 256) aggL[i] = 0u;
    for (int i = tid; i < BSZ; i += 256) degL[i] = 0;
    __syncthreads();

    const int start = gbase[b];
    const int end = start + gtotal[b];
    const int gg = tid >> 3;       // 32 groups of 8 lanes
    const int cl = tid & 7;

    for (int p0 = start + gg; p0 < end; p0 += 128) {
        const int p1 = p0 + 32, p2 = p0 + 64, p3 = p0 + 96;
        // clamped indices: duplicate max is a no-op
        const int q1 = min(p1, end - 1);
        const int q2 = min(p2, end - 1);
        const int q3 = min(p3, end - 1);
        unsigned k0 = pairs_g[p0];
        unsigned k1 = pairs_g[q1];
        unsigned k2 = pairs_g[q2];
        unsigned k3 = pairs_g[q3];
        float x0 = u[(size_t)(k0 & 0x1FFFF) * DH + c0 + cl];
        float x1 = u[(size_t)(k1 & 0x1FFFF) * DH + c0 + cl];
        float x2 = u[(size_t)(k2 & 0x1FFFF) * DH + c0 + cl];
        float x3 = u[(size_t)(k3 & 0x1FFFF) * DH + c0 + cl];
        atomicMax(&aggL[(k0 >> 17) * CPG + cl], __float_as_uint(x0));
        atomicMax(&aggL[(k1 >> 17) * CPG + cl], __float_as_uint(x1));
        atomicMax(&aggL[(k2 >> 17) * CPG + cl], __float_as_uint(x2));
        atomicMax(&aggL[(k3 >> 17) * CPG + cl], __float_as_uint(x3));
        if (cl == 0) {
            atomicAdd(&degL[k0 >> 17], 1);
            if (p1 < end) atomicAdd(&degL[k1 >> 17], 1);
            if (p2 < end) atomicAdd(&degL[k2 >> 17], 1);
            if (p3 < end) atomicAdd(&degL[k3 >> 17], 1);
        }
    }
    __syncthreads();

    for (int i = tid; i < BSZ * CPG; i += 256) {
        int vl = i >> 3;
        int v = v0 + vl;
        if (v < N) {
            float val = (degL[vl] > 1) ? __uint_as_float(aggL[i]) : 0.f;
            agg[(size_t)v * DH + c0 + (i & 7)] = val;
        }
    }
}

// ---------------------------------------------------------------------------
// out = concat(h, agg) @ W_ffnn + b_ffnn   (mask pre-applied in bucket_max)
// ---------------------------------------------------------------------------
__global__ __launch_bounds__(256) void finalize(
    const float* __restrict__ h, const float* __restrict__ agg,
    const float* __restrict__ W_ffnn, const float* __restrict__ b_ffnn,
    float* __restrict__ out, int N)
{
    __shared__ float sWt[32 * 68];
    __shared__ float sx[8][68];
    __shared__ float sb[32];

    const int tid = threadIdx.x;
    for (int i = tid; i < 64 * 32; i += 256) {
        int k = i >> 5, c = i & 31;
        sWt[c * 68 + k] = W_ffnn[i];
    }
    if (tid < 32) sb[tid] = b_ffnn[tid];

    const int g = tid >> 5, c = tid & 31;
    const int node = blockIdx.x * 8 + g;

    float hv = 0.f, av = 0.f;
    if (node < N) {
        hv = h[(size_t)node * DH + c];
        av = agg[(size_t)node * DH + c];
    }
    sx[g][c] = hv;
    sx[g][32 + c] = av;
    __syncthreads();

    float acc = sb[c];
    const float* wcol = &sWt[c * 68];
#pragma unroll
    for (int kk = 0; kk < 64; kk += 4) {
        float4 w = *(const float4*)&wcol[kk];
        float4 x = *(const float4*)&sx[g][kk];
        acc += x.x * w.x + x.y * w.y + x.z * w.z + x.w * w.w;
    }
    if (node < N) out[(size_t)node * DH + c] = acc;
}

// ---------------------------------------------------------------------------
extern "C" void kernel_launch(void* const* d_in, const int* in_sizes, int n_in,
                              void* d_out, int out_size, void* d_ws, size_t ws_size,
                              hipStream_t stream)
{
    const float* feat   = (const float*)d_in[0];
    const int*   src    = (const int*)d_in[1];
    const int*   dst    = (const int*)d_in[2];
    const float* W_in   = (const float*)d_in[3];
    const float* b_in   = (const float*)d_in[4];
    const float* W_nbr  = (const float*)d_in[5];
    const float* b_nbr  = (const float*)d_in[6];
    const float* b_n1   = (const float*)d_in[7];
    const float* W_ffnn = (const float*)d_in[8];
    const float* b_ffnn = (const float*)d_in[9];
    float* out = (float*)d_out;

    const int N = in_sizes[0] / 128;   // 100000 (N <= 131072 required by packing)
    const int E = in_sizes[1];
    const int B = (N + BSZ - 1) / BSZ; // 391 buckets (<= NBP)

    // u aliases d_out (consumed by bucket_max before finalize overwrites out)
    float* u = out;
    float* h       = (float*)d_ws;                  // N*32 f32
    float* agg     = h + (size_t)N * DH;            // N*32 f32
    int*   gtotal  = (int*)(agg + (size_t)N * DH);  // NBP
    int*   gbase   = gtotal + NBP;                  // NBP
    int*   gcursor = gbase + NBP;                   // NBP
    unsigned* pairs_g = (unsigned*)(gcursor + NBP); // 2E u32

    const int egrid = (E + SCAT_E - 1) / SCAT_E;

    zero_counts<<<(NBP + 255) / 256, 256, 0, stream>>>(gtotal);
    precount<<<egrid, 256, 0, stream>>>(src, dst, gtotal, E);
    scan_buckets<<<1, 256, 0, stream>>>(gtotal, gbase, gcursor);
    bucket_scatter<<<egrid, 256, 0, stream>>>(src, dst, gcursor, pairs_g, E, B);
    node_proj<<<(N + BN - 1) / BN, 256, 0, stream>>>(feat, W_in, b_in, W_nbr, b_nbr,
                                                     b_n1, h, u, N);
    dim3 gmax(B, NSPLIT);
    bucket_max<<<gmax, 256, 0, stream>>>(pairs_g, gbase, gtotal, u, agg, N);
    finalize<<<(N + 7) / 8, 256, 0, stream>>>(h, agg, W_ffnn, b_ffnn, out, N);
}

// Round 5
// 207.400 us; speedup vs baseline: 2.4662x; 1.1978x over previous
//
#include <hip/hip_runtime.h>
#include <hip/hip_bf16.h>

#define DH 32
#define BN 64        // nodes per block in node_proj
#define GN 8         // nodes per 32-lane group in node_proj
#define BSZ 256      // nodes per bucket
#define NBP 512      // padded bucket count (N <= 131072 => B <= 512)
#define SCAT_E 4096  // edges per scatter/precount block
#define SCAT_P (2 * SCAT_E)
#define CPG 16       // channels per sub-block in bucket_max
#define NSPLIT 2     // 32 / CPG sub-blocks per bucket

// ---------------------------------------------------------------------------
__global__ __launch_bounds__(256) void zero_counts(int* __restrict__ gtotal) {
    int i = blockIdx.x * 256 + threadIdx.x;
    if (i < NBP) gtotal[i] = 0;
}

// ---------------------------------------------------------------------------
// Per-bucket endpoint histogram.
// ---------------------------------------------------------------------------
__global__ __launch_bounds__(256) void precount(
    const int* __restrict__ src, const int* __restrict__ dst,
    int* __restrict__ gtotal, int E)
{
    __shared__ int hist[NBP];
    const int tid = threadIdx.x;
    for (int i = tid; i < NBP; i += 256) hist[i] = 0;
    __syncthreads();
    const int e0 = blockIdx.x * SCAT_E;
    const int eend = min(e0 + SCAT_E, E);
    for (int e = e0 + tid; e < eend; e += 256) {
        atomicAdd(&hist[src[e] >> 8], 1);
        atomicAdd(&hist[dst[e] >> 8], 1);
    }
    __syncthreads();
    for (int i = tid; i < NBP; i += 256)
        if (hist[i] > 0) atomicAdd(&gtotal[i], hist[i]);
}

// ---------------------------------------------------------------------------
// Exclusive scan of gtotal[0..NBP) -> gbase; gcursor = gbase. One block.
// ---------------------------------------------------------------------------
__global__ __launch_bounds__(256) void scan_buckets(
    const int* __restrict__ gtotal, int* __restrict__ gbase,
    int* __restrict__ gcursor)
{
    __shared__ int ss[256];
    const int t = threadIdx.x;
    int a = gtotal[2 * t], b = gtotal[2 * t + 1];
    int tsum = a + b;
    ss[t] = tsum;
    __syncthreads();
    for (int off = 1; off < 256; off <<= 1) {
        int y = (t >= off) ? ss[t - off] : 0;
        __syncthreads();
        ss[t] += y;
        __syncthreads();
    }
    int excl = ss[t] - tsum;
    gbase[2 * t] = excl;           gcursor[2 * t] = excl;
    gbase[2 * t + 1] = excl + a;   gcursor[2 * t + 1] = excl + a;
}

// ---------------------------------------------------------------------------
// Bucket-granular scatter: block-local sort by bucket in LDS, then coalesced
// run writes with one global cursor atomic per (block,bucket).
// pair code: (v & 255) << 17 | nbr   (requires N <= 131072)
// ---------------------------------------------------------------------------
__global__ __launch_bounds__(256) void bucket_scatter(
    const int* __restrict__ src, const int* __restrict__ dst,
    int* __restrict__ gcursor, unsigned* __restrict__ pairs_g,
    int E, int B)
{
    __shared__ unsigned s_code[SCAT_P];        // 32 KB
    __shared__ unsigned short s_bkt[SCAT_P];   // 16 KB
    __shared__ int hist[NBP], lbase[NBP], cur[NBP], gbL[NBP];  // 8 KB
    __shared__ int ss[256];

    const int tid = threadIdx.x;
    const int e0 = blockIdx.x * SCAT_E;
    const int eend = min(e0 + SCAT_E, E);
    const int np = 2 * (eend - e0);

    for (int i = tid; i < NBP; i += 256) hist[i] = 0;
    __syncthreads();

    // load up to 16 edges/thread into regs (static indexing only)
    int es[16], dr[16];
#pragma unroll
    for (int j = 0; j < 16; ++j) {
        int e = e0 + tid + j * 256;
        bool ok = (e < eend);
        es[j] = ok ? src[e] : -1;
        dr[j] = ok ? dst[e] : -1;
    }
#pragma unroll
    for (int j = 0; j < 16; ++j) {
        if (es[j] >= 0) {
            atomicAdd(&hist[es[j] >> 8], 1);
            atomicAdd(&hist[dr[j] >> 8], 1);
        }
    }
    __syncthreads();

    // exclusive scan over NBP=512 (2 elements per thread)
    {
        int a = hist[2 * tid], b = hist[2 * tid + 1];
        int tsum = a + b;
        ss[tid] = tsum;
        __syncthreads();
        for (int off = 1; off < 256; off <<= 1) {
            int y = (tid >= off) ? ss[tid - off] : 0;
            __syncthreads();
            ss[tid] += y;
            __syncthreads();
        }
        int excl = ss[tid] - tsum;
        lbase[2 * tid] = excl;         cur[2 * tid] = excl;
        lbase[2 * tid + 1] = excl + a; cur[2 * tid + 1] = excl + a;
    }
    __syncthreads();

    // rank + reorder into LDS
#pragma unroll
    for (int j = 0; j < 16; ++j) {
        if (es[j] >= 0) {
            int s = es[j], d = dr[j];
            int bs = s >> 8, bd = d >> 8;
            unsigned cs = ((unsigned)(s & 255) << 17) | (unsigned)d;
            unsigned cd = ((unsigned)(d & 255) << 17) | (unsigned)s;
            int p1 = atomicAdd(&cur[bs], 1);
            s_code[p1] = cs; s_bkt[p1] = (unsigned short)bs;
            int p2 = atomicAdd(&cur[bd], 1);
            s_code[p2] = cd; s_bkt[p2] = (unsigned short)bd;
        }
    }
    __syncthreads();

    // allocate global run per bucket
    for (int b = tid; b < B; b += 256) {
        int c = hist[b];
        if (c > 0) {
            int gw = atomicAdd(&gcursor[b], c);
            gbL[b] = gw - lbase[b];
        }
    }
    __syncthreads();

    // coalesced run writes
    for (int i = tid; i < np; i += 256) {
        int b = s_bkt[i];
        pairs_g[gbL[b] + i] = s_code[i];
    }
}

// ---------------------------------------------------------------------------
// h = feat @ W_in + b_in ; u = sigmoid(h @ W_nbr + b2)
// u is written as bf16 in channel-split layout: table q (q=c/16) is
// ub[q*N*16 + node*16 + (c&15)] — each table is N x 16 bf16 = 3.2 MB,
// sized to be XCD-L2-resident for bucket_max's gathers.
// ---------------------------------------------------------------------------
__global__ __launch_bounds__(256) void node_proj(
    const float* __restrict__ feat,
    const float* __restrict__ W_in, const float* __restrict__ b_in,
    const float* __restrict__ W_nbr, const float* __restrict__ b_nbr,
    const float* __restrict__ b_n1,
    float* __restrict__ h, unsigned short* __restrict__ ub, int N)
{
    __shared__ float sfeat[BN * 128];
    __shared__ float sWt_in[32 * 132];
    __shared__ float sWt_nbr[32 * 36];
    __shared__ float sh[BN * 32];
    __shared__ float sb_in[32], sb2[32];

    const int tid = threadIdx.x;
    const int base = blockIdx.x * BN;

    for (int i = tid; i < 128 * 32; i += 256) {
        int k = i >> 5, c = i & 31;
        sWt_in[c * 132 + k] = W_in[i];
    }
    for (int i = tid; i < 32 * 32; i += 256) {
        int k = i >> 5, c = i & 31;
        sWt_nbr[c * 36 + k] = W_nbr[i];
    }
    if (tid < 32) { sb_in[tid] = b_in[tid]; sb2[tid] = b_nbr[tid] + b_n1[tid]; }

    for (int i = tid; i < BN * 128 / 4; i += 256) {
        int row = i >> 5;
        int node = base + row;
        float4 v = make_float4(0.f, 0.f, 0.f, 0.f);
        if (node < N) v = *(const float4*)&feat[(size_t)node * 128 + (size_t)(i & 31) * 4];
        *(float4*)&sfeat[(size_t)i * 4] = v;
    }
    __syncthreads();

    const int g = tid >> 5, c = tid & 31;

    float acc[GN];
#pragma unroll
    for (int m = 0; m < GN; ++m) acc[m] = sb_in[c];

    const float* wcol = &sWt_in[c * 132];
    for (int kk = 0; kk < 128; kk += 4) {
        float4 w = *(const float4*)&wcol[kk];
#pragma unroll
        for (int m = 0; m < GN; ++m) {
            float4 f = *(const float4*)&sfeat[(g * GN + m) * 128 + kk];
            acc[m] += f.x * w.x + f.y * w.y + f.z * w.z + f.w * w.w;
        }
    }

#pragma unroll
    for (int m = 0; m < GN; ++m) {
        int node = base + g * GN + m;
        sh[(g * GN + m) * 32 + c] = acc[m];
        if (node < N) h[(size_t)node * 32 + c] = acc[m];
    }
    __syncthreads();

    float acc2[GN];
#pragma unroll
    for (int m = 0; m < GN; ++m) acc2[m] = sb2[c];

    const float* wcol2 = &sWt_nbr[c * 36];
    for (int kk = 0; kk < 32; kk += 4) {
        float4 w = *(const float4*)&wcol2[kk];
#pragma unroll
        for (int m = 0; m < GN; ++m) {
            float4 hf = *(const float4*)&sh[(g * GN + m) * 32 + kk];
            acc2[m] += hf.x * w.x + hf.y * w.y + hf.z * w.z + hf.w * w.w;
        }
    }

#pragma unroll
    for (int m = 0; m < GN; ++m) {
        int node = base + g * GN + m;
        if (node < N) {
            float s = 1.0f / (1.0f + __expf(-acc2[m]));
            // bf16 round-to-nearest: take top 16 bits with rounding
            unsigned bits = __float_as_uint(s);
            bits += 0x7FFFu + ((bits >> 16) & 1u);   // RNE
            ub[((size_t)(c >> 4) * N + node) * CPG + (c & 15)] =
                (unsigned short)(bits >> 16);
        }
    }
}

// ---------------------------------------------------------------------------
// Per-bucket segment max in LDS, split 2 ways by channel half.
// Sub-block q gathers 32B rows from ITS OWN 3.2MB bf16 table (L2-resident).
// 16-lane group per pair; pair loop unrolled 4x (clamped duplicate gathers
// are no-ops for max; deg increments guarded).
// ---------------------------------------------------------------------------
__global__ __launch_bounds__(256) void bucket_max(
    const unsigned* __restrict__ pairs_g, const int* __restrict__ gbase,
    const int* __restrict__ gtotal, const unsigned short* __restrict__ ub,
    float* __restrict__ agg, int N)
{
    __shared__ unsigned aggL[BSZ * CPG];   // 16 KB
    __shared__ int degL[BSZ];              // 1 KB

    const int tid = threadIdx.x;
    const int b = blockIdx.x;
    const int q = blockIdx.y;              // channel half
    const int v0 = b * BSZ;
    const unsigned short* ut = ub + (size_t)q * N * CPG;

    for (int i = tid; i < BSZ * CPG; i += 256) aggL[i] = 0u;
    for (int i = tid; i < BSZ; i += 256) degL[i] = 0;
    __syncthreads();

    const int start = gbase[b];
    const int end = start + gtotal[b];
    const int gg = tid >> 4;       // 16 groups of 16 lanes
    const int cl = tid & 15;

    for (int p0 = start + gg; p0 < end; p0 += 64) {
        const int p1 = p0 + 16, p2 = p0 + 32, p3 = p0 + 48;
        const int q1 = min(p1, end - 1);
        const int q2 = min(p2, end - 1);
        const int q3 = min(p3, end - 1);
        unsigned k0 = pairs_g[p0];
        unsigned k1 = pairs_g[q1];
        unsigned k2 = pairs_g[q2];
        unsigned k3 = pairs_g[q3];
        // bf16 bits << 16 == f32 bits of the bf16 value; positive -> uint order
        unsigned x0 = (unsigned)ut[(size_t)(k0 & 0x1FFFF) * CPG + cl] << 16;
        unsigned x1 = (unsigned)ut[(size_t)(k1 & 0x1FFFF) * CPG + cl] << 16;
        unsigned x2 = (unsigned)ut[(size_t)(k2 & 0x1FFFF) * CPG + cl] << 16;
        unsigned x3 = (unsigned)ut[(size_t)(k3 & 0x1FFFF) * CPG + cl] << 16;
        atomicMax(&aggL[(k0 >> 17) * CPG + cl], x0);
        atomicMax(&aggL[(k1 >> 17) * CPG + cl], x1);
        atomicMax(&aggL[(k2 >> 17) * CPG + cl], x2);
        atomicMax(&aggL[(k3 >> 17) * CPG + cl], x3);
        if (cl == 0) {
            atomicAdd(&degL[k0 >> 17], 1);
            if (p1 < end) atomicAdd(&degL[k1 >> 17], 1);
            if (p2 < end) atomicAdd(&degL[k2 >> 17], 1);
            if (p3 < end) atomicAdd(&degL[k3 >> 17], 1);
        }
    }
    __syncthreads();

    for (int i = tid; i < BSZ * CPG; i += 256) {
        int vl = i >> 4;
        int v = v0 + vl;
        if (v < N) {
            float val = (degL[vl] > 1) ? __uint_as_float(aggL[i]) : 0.f;
            agg[(size_t)v * DH + q * CPG + (i & 15)] = val;
        }
    }
}

// ---------------------------------------------------------------------------
// out = concat(h, agg) @ W_ffnn + b_ffnn   (mask pre-applied in bucket_max)
// ---------------------------------------------------------------------------
__global__ __launch_bounds__(256) void finalize(
    const float* __restrict__ h, const float* __restrict__ agg,
    const float* __restrict__ W_ffnn, const float* __restrict__ b_ffnn,
    float* __restrict__ out, int N)
{
    __shared__ float sWt[32 * 68];
    __shared__ float sx[8][68];
    __shared__ float sb[32];

    const int tid = threadIdx.x;
    for (int i = tid; i < 64 * 32; i += 256) {
        int k = i >> 5, c = i & 31;
        sWt[c * 68 + k] = W_ffnn[i];
    }
    if (tid < 32) sb[tid] = b_ffnn[tid];

    const int g = tid >> 5, c = tid & 31;
    const int node = blockIdx.x * 8 + g;

    float hv = 0.f, av = 0.f;
    if (node < N) {
        hv = h[(size_t)node * DH + c];
        av = agg[(size_t)node * DH + c];
    }
    sx[g][c] = hv;
    sx[g][32 + c] = av;
    __syncthreads();

    float acc = sb[c];
    const float* wcol = &sWt[c * 68];
#pragma unroll
    for (int kk = 0; kk < 64; kk += 4) {
        float4 w = *(const float4*)&wcol[kk];
        float4 x = *(const float4*)&sx[g][kk];
        acc += x.x * w.x + x.y * w.y + x.z * w.z + x.w * w.w;
    }
    if (node < N) out[(size_t)node * DH + c] = acc;
}

// ---------------------------------------------------------------------------
extern "C" void kernel_launch(void* const* d_in, const int* in_sizes, int n_in,
                              void* d_out, int out_size, void* d_ws, size_t ws_size,
                              hipStream_t stream)
{
    const float* feat   = (const float*)d_in[0];
    const int*   src    = (const int*)d_in[1];
    const int*   dst    = (const int*)d_in[2];
    const float* W_in   = (const float*)d_in[3];
    const float* b_in   = (const float*)d_in[4];
    const float* W_nbr  = (const float*)d_in[5];
    const float* b_nbr  = (const float*)d_in[6];
    const float* b_n1   = (const float*)d_in[7];
    const float* W_ffnn = (const float*)d_in[8];
    const float* b_ffnn = (const float*)d_in[9];
    float* out = (float*)d_out;

    const int N = in_sizes[0] / 128;   // 100000 (N <= 131072 required by packing)
    const int E = in_sizes[1];
    const int B = (N + BSZ - 1) / BSZ; // 391 buckets (<= NBP)

    // u (bf16, channel-split, 6.4MB) aliases d_out (12.8MB): written by
    // node_proj, consumed by bucket_max, then finalize overwrites out.
    unsigned short* ub = (unsigned short*)out;
    float* h       = (float*)d_ws;                  // N*32 f32
    float* agg     = h + (size_t)N * DH;            // N*32 f32
    int*   gtotal  = (int*)(agg + (size_t)N * DH);  // NBP
    int*   gbase   = gtotal + NBP;                  // NBP
    int*   gcursor = gbase + NBP;                   // NBP
    unsigned* pairs_g = (unsigned*)(gcursor + NBP); // 2E u32

    const int egrid = (E + SCAT_E - 1) / SCAT_E;

    zero_counts<<<(NBP + 255) / 256, 256, 0, stream>>>(gtotal);
    precount<<<egrid, 256, 0, stream>>>(src, dst, gtotal, E);
    scan_buckets<<<1, 256, 0, stream>>>(gtotal, gbase, gcursor);
    bucket_scatter<<<egrid, 256, 0, stream>>>(src, dst, gcursor, pairs_g, E, B);
    node_proj<<<(N + BN - 1) / BN, 256, 0, stream>>>(feat, W_in, b_in, W_nbr, b_nbr,
                                                     b_n1, h, ub, N);
    dim3 gmax(B, NSPLIT);
    bucket_max<<<gmax, 256, 0, stream>>>(pairs_g, gbase, gtotal, ub, agg, N);
    finalize<<<(N + 7) / 8, 256, 0, stream>>>(h, agg, W_ffnn, b_ffnn, out, N);
}

// Round 6
// 161.631 us; speedup vs baseline: 3.1646x; 1.2832x over previous
//
#include <hip/hip_runtime.h>
#include <hip/hip_bf16.h>

#define DH 32
#define BSZ 256      // nodes per bucket
#define NBP 512      // padded bucket count (N <= 131072 => B <= 512)
#define SCAT_E 4096  // edges per scatter/precount block
#define SCAT_P (2 * SCAT_E)
#define CPG 16       // channels per sub-block in bucket_max
#define NSPLIT 2     // 32 / CPG sub-blocks per bucket

// ---------------------------------------------------------------------------
__global__ __launch_bounds__(256) void zero_counts(int* __restrict__ gtotal) {
    int i = blockIdx.x * 256 + threadIdx.x;
    if (i < NBP) gtotal[i] = 0;
}

// ---------------------------------------------------------------------------
// Per-bucket endpoint histogram.
// ---------------------------------------------------------------------------
__global__ __launch_bounds__(256) void precount(
    const int* __restrict__ src, const int* __restrict__ dst,
    int* __restrict__ gtotal, int E)
{
    __shared__ int hist[NBP];
    const int tid = threadIdx.x;
    for (int i = tid; i < NBP; i += 256) hist[i] = 0;
    __syncthreads();
    const int e0 = blockIdx.x * SCAT_E;
    const int eend = min(e0 + SCAT_E, E);
    for (int e = e0 + tid; e < eend; e += 256) {
        atomicAdd(&hist[src[e] >> 8], 1);
        atomicAdd(&hist[dst[e] >> 8], 1);
    }
    __syncthreads();
    for (int i = tid; i < NBP; i += 256)
        if (hist[i] > 0) atomicAdd(&gtotal[i], hist[i]);
}

// ---------------------------------------------------------------------------
// Exclusive scan of gtotal[0..NBP) -> gbase; gcursor = gbase. One block.
// ---------------------------------------------------------------------------
__global__ __launch_bounds__(256) void scan_buckets(
    const int* __restrict__ gtotal, int* __restrict__ gbase,
    int* __restrict__ gcursor)
{
    __shared__ int ss[256];
    const int t = threadIdx.x;
    int a = gtotal[2 * t], b = gtotal[2 * t + 1];
    int tsum = a + b;
    ss[t] = tsum;
    __syncthreads();
    for (int off = 1; off < 256; off <<= 1) {
        int y = (t >= off) ? ss[t - off] : 0;
        __syncthreads();
        ss[t] += y;
        __syncthreads();
    }
    int excl = ss[t] - tsum;
    gbase[2 * t] = excl;           gcursor[2 * t] = excl;
    gbase[2 * t + 1] = excl + a;   gcursor[2 * t + 1] = excl + a;
}

// ---------------------------------------------------------------------------
// Bucket-granular scatter: block-local sort by bucket in LDS, then coalesced
// run writes with one global cursor atomic per (block,bucket).
// pair code: (v & 255) << 17 | nbr   (requires N <= 131072)
// ---------------------------------------------------------------------------
__global__ __launch_bounds__(256) void bucket_scatter(
    const int* __restrict__ src, const int* __restrict__ dst,
    int* __restrict__ gcursor, unsigned* __restrict__ pairs_g,
    int E, int B)
{
    __shared__ unsigned s_code[SCAT_P];        // 32 KB
    __shared__ unsigned short s_bkt[SCAT_P];   // 16 KB
    __shared__ int hist[NBP], lbase[NBP], cur[NBP], gbL[NBP];  // 8 KB
    __shared__ int ss[256];

    const int tid = threadIdx.x;
    const int e0 = blockIdx.x * SCAT_E;
    const int eend = min(e0 + SCAT_E, E);
    const int np = 2 * (eend - e0);

    for (int i = tid; i < NBP; i += 256) hist[i] = 0;
    __syncthreads();

    // load up to 16 edges/thread into regs (static indexing only)
    int es[16], dr[16];
#pragma unroll
    for (int j = 0; j < 16; ++j) {
        int e = e0 + tid + j * 256;
        bool ok = (e < eend);
        es[j] = ok ? src[e] : -1;
        dr[j] = ok ? dst[e] : -1;
    }
#pragma unroll
    for (int j = 0; j < 16; ++j) {
        if (es[j] >= 0) {
            atomicAdd(&hist[es[j] >> 8], 1);
            atomicAdd(&hist[dr[j] >> 8], 1);
        }
    }
    __syncthreads();

    // exclusive scan over NBP=512 (2 elements per thread)
    {
        int a = hist[2 * tid], b = hist[2 * tid + 1];
        int tsum = a + b;
        ss[tid] = tsum;
        __syncthreads();
        for (int off = 1; off < 256; off <<= 1) {
            int y = (tid >= off) ? ss[tid - off] : 0;
            __syncthreads();
            ss[tid] += y;
            __syncthreads();
        }
        int excl = ss[tid] - tsum;
        lbase[2 * tid] = excl;         cur[2 * tid] = excl;
        lbase[2 * tid + 1] = excl + a; cur[2 * tid + 1] = excl + a;
    }
    __syncthreads();

    // rank + reorder into LDS
#pragma unroll
    for (int j = 0; j < 16; ++j) {
        if (es[j] >= 0) {
            int s = es[j], d = dr[j];
            int bs = s >> 8, bd = d >> 8;
            unsigned cs = ((unsigned)(s & 255) << 17) | (unsigned)d;
            unsigned cd = ((unsigned)(d & 255) << 17) | (unsigned)s;
            int p1 = atomicAdd(&cur[bs], 1);
            s_code[p1] = cs; s_bkt[p1] = (unsigned short)bs;
            int p2 = atomicAdd(&cur[bd], 1);
            s_code[p2] = cd; s_bkt[p2] = (unsigned short)bd;
        }
    }
    __syncthreads();

    // allocate global run per bucket
    for (int b = tid; b < B; b += 256) {
        int c = hist[b];
        if (c > 0) {
            int gw = atomicAdd(&gcursor[b], c);
            gbL[b] = gw - lbase[b];
        }
    }
    __syncthreads();

    // coalesced run writes
    for (int i = tid; i < np; i += 256) {
        int b = s_bkt[i];
        pairs_g[gbL[b] + i] = s_code[i];
    }
}

// ---------------------------------------------------------------------------
// One THREAD per node. Weights staged in LDS and read at wave-uniform
// addresses (broadcast, conflict-free); feat row / h / u live in registers.
//   h = feat @ W_in + b_in                  (128 -> 32)
//   u = sigmoid(h @ W_nbr + b_nbr + b_n1)   (32 -> 32), bf16 channel-split
// All register arrays statically indexed (full unroll where needed).
// ---------------------------------------------------------------------------
__global__ __launch_bounds__(128) void node_proj(
    const float* __restrict__ feat,
    const float* __restrict__ W_in, const float* __restrict__ b_in,
    const float* __restrict__ W_nbr, const float* __restrict__ b_nbr,
    const float* __restrict__ b_n1,
    float* __restrict__ h, unsigned short* __restrict__ ub, int N)
{
    __shared__ float sW1[128 * 32];   // [k][c] natural layout, 16 KB
    __shared__ float sW2[32 * 32];    // [k][c], 4 KB
    __shared__ float sb1[32], sb2[32];

    const int tid = threadIdx.x;
    for (int i = tid; i < 128 * 32; i += 128) sW1[i] = W_in[i];
    for (int i = tid; i < 32 * 32; i += 128) sW2[i] = W_nbr[i];
    if (tid < 32) { sb1[tid] = b_in[tid]; sb2[tid] = b_nbr[tid] + b_n1[tid]; }
    __syncthreads();

    const int node = blockIdx.x * 128 + tid;
    if (node >= N) return;

    const float4* frow = (const float4*)(feat + (size_t)node * 128);

    float acc[32];
#pragma unroll
    for (int c = 0; c < 32; ++c) acc[c] = sb1[c];

    // GEMM1: per k, all lanes broadcast-read the same w row from LDS.
#pragma unroll 4
    for (int k4 = 0; k4 < 32; ++k4) {
        const float4 f = frow[k4];
        const float4* w0 = (const float4*)&sW1[(k4 * 4 + 0) * 32];
        const float4* w1 = (const float4*)&sW1[(k4 * 4 + 1) * 32];
        const float4* w2 = (const float4*)&sW1[(k4 * 4 + 2) * 32];
        const float4* w3 = (const float4*)&sW1[(k4 * 4 + 3) * 32];
#pragma unroll
        for (int c4 = 0; c4 < 8; ++c4) {
            float4 a0 = w0[c4], a1 = w1[c4], a2 = w2[c4], a3 = w3[c4];
            acc[c4 * 4 + 0] = fmaf(f.w, a3.x, fmaf(f.z, a2.x, fmaf(f.y, a1.x, fmaf(f.x, a0.x, acc[c4 * 4 + 0]))));
            acc[c4 * 4 + 1] = fmaf(f.w, a3.y, fmaf(f.z, a2.y, fmaf(f.y, a1.y, fmaf(f.x, a0.y, acc[c4 * 4 + 1]))));
            acc[c4 * 4 + 2] = fmaf(f.w, a3.z, fmaf(f.z, a2.z, fmaf(f.y, a1.z, fmaf(f.x, a0.z, acc[c4 * 4 + 2]))));
            acc[c4 * 4 + 3] = fmaf(f.w, a3.w, fmaf(f.z, a2.w, fmaf(f.y, a1.w, fmaf(f.x, a0.w, acc[c4 * 4 + 3]))));
        }
    }

    // store h row (registers -> own row, float4)
    {
        float4* hrow = (float4*)(h + (size_t)node * 32);
#pragma unroll
        for (int c4 = 0; c4 < 8; ++c4)
            hrow[c4] = make_float4(acc[c4 * 4 + 0], acc[c4 * 4 + 1],
                                   acc[c4 * 4 + 2], acc[c4 * 4 + 3]);
    }

    // GEMM2 on register-resident h (fully unrolled: static acc[] indexing)
    float acc2[32];
#pragma unroll
    for (int c = 0; c < 32; ++c) acc2[c] = sb2[c];
#pragma unroll
    for (int k = 0; k < 32; ++k) {
        const float hv = acc[k];
        const float4* wr = (const float4*)&sW2[k * 32];
#pragma unroll
        for (int c4 = 0; c4 < 8; ++c4) {
            float4 w = wr[c4];
            acc2[c4 * 4 + 0] = fmaf(hv, w.x, acc2[c4 * 4 + 0]);
            acc2[c4 * 4 + 1] = fmaf(hv, w.y, acc2[c4 * 4 + 1]);
            acc2[c4 * 4 + 2] = fmaf(hv, w.z, acc2[c4 * 4 + 2]);
            acc2[c4 * 4 + 3] = fmaf(hv, w.w, acc2[c4 * 4 + 3]);
        }
    }

    // sigmoid -> bf16 (RNE) -> channel-split tables, packed uint writes
    unsigned* ub32 = (unsigned*)ub;
#pragma unroll
    for (int j = 0; j < 16; ++j) {
        const int q = j >> 3, jj = j & 7;
        const int c = q * 16 + 2 * jj;
        float s0 = 1.0f / (1.0f + __expf(-acc2[c]));
        float s1 = 1.0f / (1.0f + __expf(-acc2[c + 1]));
        unsigned b0 = __float_as_uint(s0);
        b0 += 0x7FFFu + ((b0 >> 16) & 1u);
        unsigned b1 = __float_as_uint(s1);
        b1 += 0x7FFFu + ((b1 >> 16) & 1u);
        ub32[((size_t)q * N + node) * 8 + jj] = (b0 >> 16) | (b1 & 0xFFFF0000u);
    }
}

// ---------------------------------------------------------------------------
// Per-bucket segment max in LDS, split 2 ways by channel half.
// Sub-block q gathers 32B rows from ITS OWN 3.2MB bf16 table (L2-resident).
// ---------------------------------------------------------------------------
__global__ __launch_bounds__(256) void bucket_max(
    const unsigned* __restrict__ pairs_g, const int* __restrict__ gbase,
    const int* __restrict__ gtotal, const unsigned short* __restrict__ ub,
    float* __restrict__ agg, int N)
{
    __shared__ unsigned aggL[BSZ * CPG];   // 16 KB
    __shared__ int degL[BSZ];              // 1 KB

    const int tid = threadIdx.x;
    const int b = blockIdx.x;
    const int q = blockIdx.y;              // channel half
    const int v0 = b * BSZ;
    const unsigned short* ut = ub + (size_t)q * N * CPG;

    for (int i = tid; i < BSZ * CPG; i += 256) aggL[i] = 0u;
    for (int i = tid; i < BSZ; i += 256) degL[i] = 0;
    __syncthreads();

    const int start = gbase[b];
    const int end = start + gtotal[b];
    const int gg = tid >> 4;       // 16 groups of 16 lanes
    const int cl = tid & 15;

    for (int p0 = start + gg; p0 < end; p0 += 64) {
        const int p1 = p0 + 16, p2 = p0 + 32, p3 = p0 + 48;
        const int q1 = min(p1, end - 1);
        const int q2 = min(p2, end - 1);
        const int q3 = min(p3, end - 1);
        unsigned k0 = pairs_g[p0];
        unsigned k1 = pairs_g[q1];
        unsigned k2 = pairs_g[q2];
        unsigned k3 = pairs_g[q3];
        // bf16 bits << 16 == f32 bits of the bf16 value; positive -> uint order
        unsigned x0 = (unsigned)ut[(size_t)(k0 & 0x1FFFF) * CPG + cl] << 16;
        unsigned x1 = (unsigned)ut[(size_t)(k1 & 0x1FFFF) * CPG + cl] << 16;
        unsigned x2 = (unsigned)ut[(size_t)(k2 & 0x1FFFF) * CPG + cl] << 16;
        unsigned x3 = (unsigned)ut[(size_t)(k3 & 0x1FFFF) * CPG + cl] << 16;
        atomicMax(&aggL[(k0 >> 17) * CPG + cl], x0);
        atomicMax(&aggL[(k1 >> 17) * CPG + cl], x1);
        atomicMax(&aggL[(k2 >> 17) * CPG + cl], x2);
        atomicMax(&aggL[(k3 >> 17) * CPG + cl], x3);
        if (cl == 0) {
            atomicAdd(&degL[k0 >> 17], 1);
            if (p1 < end) atomicAdd(&degL[k1 >> 17], 1);
            if (p2 < end) atomicAdd(&degL[k2 >> 17], 1);
            if (p3 < end) atomicAdd(&degL[k3 >> 17], 1);
        }
    }
    __syncthreads();

    for (int i = tid; i < BSZ * CPG; i += 256) {
        int vl = i >> 4;
        int v = v0 + vl;
        if (v < N) {
            float val = (degL[vl] > 1) ? __uint_as_float(aggL[i]) : 0.f;
            agg[(size_t)v * DH + q * CPG + (i & 15)] = val;
        }
    }
}

// ---------------------------------------------------------------------------
// One THREAD per node: out = concat(h, agg) @ W_ffnn + b_ffnn.
// W_ffnn broadcast from LDS; h/agg rows in registers (no LDS tiles).
// ---------------------------------------------------------------------------
__global__ __launch_bounds__(128) void finalize(
    const float* __restrict__ h, const float* __restrict__ agg,
    const float* __restrict__ W_ffnn, const float* __restrict__ b_ffnn,
    float* __restrict__ out, int N)
{
    __shared__ float sW[64 * 32];   // [k][c] natural layout, 8 KB
    __shared__ float sb[32];

    const int tid = threadIdx.x;
    for (int i = tid; i < 64 * 32; i += 128) sW[i] = W_ffnn[i];
    if (tid < 32) sb[tid] = b_ffnn[tid];
    __syncthreads();

    const int node = blockIdx.x * 128 + tid;
    if (node >= N) return;

    const float4* hrow = (const float4*)(h + (size_t)node * 32);
    const float4* arow = (const float4*)(agg + (size_t)node * 32);

    float acc[32];
#pragma unroll
    for (int c = 0; c < 32; ++c) acc[c] = sb[c];

#pragma unroll 2
    for (int k4 = 0; k4 < 8; ++k4) {
        const float4 f = hrow[k4];
        const float4* w0 = (const float4*)&sW[(k4 * 4 + 0) * 32];
        const float4* w1 = (const float4*)&sW[(k4 * 4 + 1) * 32];
        const float4* w2 = (const float4*)&sW[(k4 * 4 + 2) * 32];
        const float4* w3 = (const float4*)&sW[(k4 * 4 + 3) * 32];
#pragma unroll
        for (int c4 = 0; c4 < 8; ++c4) {
            float4 a0 = w0[c4], a1 = w1[c4], a2 = w2[c4], a3 = w3[c4];
            acc[c4 * 4 + 0] = fmaf(f.w, a3.x, fmaf(f.z, a2.x, fmaf(f.y, a1.x, fmaf(f.x, a0.x, acc[c4 * 4 + 0]))));
            acc[c4 * 4 + 1] = fmaf(f.w, a3.y, fmaf(f.z, a2.y, fmaf(f.y, a1.y, fmaf(f.x, a0.y, acc[c4 * 4 + 1]))));
            acc[c4 * 4 + 2] = fmaf(f.w, a3.z, fmaf(f.z, a2.z, fmaf(f.y, a1.z, fmaf(f.x, a0.z, acc[c4 * 4 + 2]))));
            acc[c4 * 4 + 3] = fmaf(f.w, a3.w, fmaf(f.z, a2.w, fmaf(f.y, a1.w, fmaf(f.x, a0.w, acc[c4 * 4 + 3]))));
        }
    }
#pragma unroll 2
    for (int k4 = 0; k4 < 8; ++k4) {
        const float4 f = arow[k4];
        const float4* w0 = (const float4*)&sW[(32 + k4 * 4 + 0) * 32];
        const float4* w1 = (const float4*)&sW[(32 + k4 * 4 + 1) * 32];
        const float4* w2 = (const float4*)&sW[(32 + k4 * 4 + 2) * 32];
        const float4* w3 = (const float4*)&sW[(32 + k4 * 4 + 3) * 32];
#pragma unroll
        for (int c4 = 0; c4 < 8; ++c4) {
            float4 a0 = w0[c4], a1 = w1[c4], a2 = w2[c4], a3 = w3[c4];
            acc[c4 * 4 + 0] = fmaf(f.w, a3.x, fmaf(f.z, a2.x, fmaf(f.y, a1.x, fmaf(f.x, a0.x, acc[c4 * 4 + 0]))));
            acc[c4 * 4 + 1] = fmaf(f.w, a3.y, fmaf(f.z, a2.y, fmaf(f.y, a1.y, fmaf(f.x, a0.y, acc[c4 * 4 + 1]))));
            acc[c4 * 4 + 2] = fmaf(f.w, a3.z, fmaf(f.z, a2.z, fmaf(f.y, a1.z, fmaf(f.x, a0.z, acc[c4 * 4 + 2]))));
            acc[c4 * 4 + 3] = fmaf(f.w, a3.w, fmaf(f.z, a2.w, fmaf(f.y, a1.w, fmaf(f.x, a0.w, acc[c4 * 4 + 3]))));
        }
    }

    float4* orow = (float4*)(out + (size_t)node * 32);
#pragma unroll
    for (int c4 = 0; c4 < 8; ++c4)
        orow[c4] = make_float4(acc[c4 * 4 + 0], acc[c4 * 4 + 1],
                               acc[c4 * 4 + 2], acc[c4 * 4 + 3]);
}

// ---------------------------------------------------------------------------
extern "C" void kernel_launch(void* const* d_in, const int* in_sizes, int n_in,
                              void* d_out, int out_size, void* d_ws, size_t ws_size,
                              hipStream_t stream)
{
    const float* feat   = (const float*)d_in[0];
    const int*   src    = (const int*)d_in[1];
    const int*   dst    = (const int*)d_in[2];
    const float* W_in   = (const float*)d_in[3];
    const float* b_in   = (const float*)d_in[4];
    const float* W_nbr  = (const float*)d_in[5];
    const float* b_nbr  = (const float*)d_in[6];
    const float* b_n1   = (const float*)d_in[7];
    const float* W_ffnn = (const float*)d_in[8];
    const float* b_ffnn = (const float*)d_in[9];
    float* out = (float*)d_out;

    const int N = in_sizes[0] / 128;   // 100000 (N <= 131072 required by packing)
    const int E = in_sizes[1];
    const int B = (N + BSZ - 1) / BSZ; // 391 buckets (<= NBP)

    // u (bf16, channel-split, 6.4MB) aliases d_out (12.8MB): written by
    // node_proj, consumed by bucket_max, then finalize overwrites out.
    unsigned short* ub = (unsigned short*)out;
    float* h       = (float*)d_ws;                  // N*32 f32
    float* agg     = h + (size_t)N * DH;            // N*32 f32
    int*   gtotal  = (int*)(agg + (size_t)N * DH);  // NBP
    int*   gbase   = gtotal + NBP;                  // NBP
    int*   gcursor = gbase + NBP;                   // NBP
    unsigned* pairs_g = (unsigned*)(gcursor + NBP); // 2E u32

    const int egrid = (E + SCAT_E - 1) / SCAT_E;

    zero_counts<<<(NBP + 255) / 256, 256, 0, stream>>>(gtotal);
    precount<<<egrid, 256, 0, stream>>>(src, dst, gtotal, E);
    scan_buckets<<<1, 256, 0, stream>>>(gtotal, gbase, gcursor);
    bucket_scatter<<<egrid, 256, 0, stream>>>(src, dst, gcursor, pairs_g, E, B);
    node_proj<<<(N + 127) / 128, 128, 0, stream>>>(feat, W_in, b_in, W_nbr, b_nbr,
                                                   b_n1, h, ub, N);
    dim3 gmax(B, NSPLIT);
    bucket_max<<<gmax, 256, 0, stream>>>(pairs_g, gbase, gtotal, ub, agg, N);
    finalize<<<(N + 127) / 128, 128, 0, stream>>>(h, agg, W_ffnn, b_ffnn, out, N);
}

// Round 7
// 133.759 us; speedup vs baseline: 3.8240x; 1.2084x over previous
//
#include <hip/hip_runtime.h>
#include <hip/hip_bf16.h>

#define DH 32
#define BSZ 256      // nodes per bucket
#define NBP 512      // padded bucket count (N <= 131072 => B <= 512)
#define SCAT_E 4096  // edges per scatter/precount block
#define SCAT_P (2 * SCAT_E)
#define CPG 16       // channels per sub-block in bucket_max
#define NSPLIT 2     // 32 / CPG sub-blocks per bucket
#define TS 2048      // pair codes per LDS tile in bucket_max

// ---------------------------------------------------------------------------
__global__ __launch_bounds__(256) void zero_counts(int* __restrict__ gtotal) {
    int i = blockIdx.x * 256 + threadIdx.x;
    if (i < NBP) gtotal[i] = 0;
}

// ---------------------------------------------------------------------------
// Per-bucket endpoint histogram.
// ---------------------------------------------------------------------------
__global__ __launch_bounds__(256) void precount(
    const int* __restrict__ src, const int* __restrict__ dst,
    int* __restrict__ gtotal, int E)
{
    __shared__ int hist[NBP];
    const int tid = threadIdx.x;
    for (int i = tid; i < NBP; i += 256) hist[i] = 0;
    __syncthreads();
    const int e0 = blockIdx.x * SCAT_E;
    const int eend = min(e0 + SCAT_E, E);
    for (int e = e0 + tid; e < eend; e += 256) {
        atomicAdd(&hist[src[e] >> 8], 1);
        atomicAdd(&hist[dst[e] >> 8], 1);
    }
    __syncthreads();
    for (int i = tid; i < NBP; i += 256)
        if (hist[i] > 0) atomicAdd(&gtotal[i], hist[i]);
}

// ---------------------------------------------------------------------------
// Exclusive scan of gtotal[0..NBP) -> gbase; gcursor = gbase. One block.
// ---------------------------------------------------------------------------
__global__ __launch_bounds__(256) void scan_buckets(
    const int* __restrict__ gtotal, int* __restrict__ gbase,
    int* __restrict__ gcursor)
{
    __shared__ int ss[256];
    const int t = threadIdx.x;
    int a = gtotal[2 * t], b = gtotal[2 * t + 1];
    int tsum = a + b;
    ss[t] = tsum;
    __syncthreads();
    for (int off = 1; off < 256; off <<= 1) {
        int y = (t >= off) ? ss[t - off] : 0;
        __syncthreads();
        ss[t] += y;
        __syncthreads();
    }
    int excl = ss[t] - tsum;
    gbase[2 * t] = excl;           gcursor[2 * t] = excl;
    gbase[2 * t + 1] = excl + a;   gcursor[2 * t + 1] = excl + a;
}

// ---------------------------------------------------------------------------
// Bucket-granular scatter: block-local sort by bucket in LDS, then coalesced
// run writes with one global cursor atomic per (block,bucket).
// pair code: (v & 255) << 17 | nbr   (requires N <= 131072)
// ---------------------------------------------------------------------------
__global__ __launch_bounds__(256) void bucket_scatter(
    const int* __restrict__ src, const int* __restrict__ dst,
    int* __restrict__ gcursor, unsigned* __restrict__ pairs_g,
    int E, int B)
{
    __shared__ unsigned s_code[SCAT_P];        // 32 KB
    __shared__ unsigned short s_bkt[SCAT_P];   // 16 KB
    __shared__ int hist[NBP], lbase[NBP], cur[NBP], gbL[NBP];  // 8 KB
    __shared__ int ss[256];

    const int tid = threadIdx.x;
    const int e0 = blockIdx.x * SCAT_E;
    const int eend = min(e0 + SCAT_E, E);
    const int np = 2 * (eend - e0);

    for (int i = tid; i < NBP; i += 256) hist[i] = 0;
    __syncthreads();

    // load up to 16 edges/thread into regs (static indexing only)
    int es[16], dr[16];
#pragma unroll
    for (int j = 0; j < 16; ++j) {
        int e = e0 + tid + j * 256;
        bool ok = (e < eend);
        es[j] = ok ? src[e] : -1;
        dr[j] = ok ? dst[e] : -1;
    }
#pragma unroll
    for (int j = 0; j < 16; ++j) {
        if (es[j] >= 0) {
            atomicAdd(&hist[es[j] >> 8], 1);
            atomicAdd(&hist[dr[j] >> 8], 1);
        }
    }
    __syncthreads();

    // exclusive scan over NBP=512 (2 elements per thread)
    {
        int a = hist[2 * tid], b = hist[2 * tid + 1];
        int tsum = a + b;
        ss[tid] = tsum;
        __syncthreads();
        for (int off = 1; off < 256; off <<= 1) {
            int y = (tid >= off) ? ss[tid - off] : 0;
            __syncthreads();
            ss[tid] += y;
            __syncthreads();
        }
        int excl = ss[tid] - tsum;
        lbase[2 * tid] = excl;         cur[2 * tid] = excl;
        lbase[2 * tid + 1] = excl + a; cur[2 * tid + 1] = excl + a;
    }
    __syncthreads();

    // rank + reorder into LDS
#pragma unroll
    for (int j = 0; j < 16; ++j) {
        if (es[j] >= 0) {
            int s = es[j], d = dr[j];
            int bs = s >> 8, bd = d >> 8;
            unsigned cs = ((unsigned)(s & 255) << 17) | (unsigned)d;
            unsigned cd = ((unsigned)(d & 255) << 17) | (unsigned)s;
            int p1 = atomicAdd(&cur[bs], 1);
            s_code[p1] = cs; s_bkt[p1] = (unsigned short)bs;
            int p2 = atomicAdd(&cur[bd], 1);
            s_code[p2] = cd; s_bkt[p2] = (unsigned short)bd;
        }
    }
    __syncthreads();

    // allocate global run per bucket
    for (int b = tid; b < B; b += 256) {
        int c = hist[b];
        if (c > 0) {
            int gw = atomicAdd(&gcursor[b], c);
            gbL[b] = gw - lbase[b];
        }
    }
    __syncthreads();

    // coalesced run writes
    for (int i = tid; i < np; i += 256) {
        int b = s_bkt[i];
        pairs_g[gbL[b] + i] = s_code[i];
    }
}

// ---------------------------------------------------------------------------
// One THREAD per node. Weights staged in LDS and read at wave-uniform
// addresses (broadcast, conflict-free); feat row / h / u live in registers.
//   h = feat @ W_in + b_in                  (128 -> 32)
//   u = sigmoid(h @ W_nbr + b_nbr + b_n1)   (32 -> 32), bf16 channel-split
// ---------------------------------------------------------------------------
__global__ __launch_bounds__(128) void node_proj(
    const float* __restrict__ feat,
    const float* __restrict__ W_in, const float* __restrict__ b_in,
    const float* __restrict__ W_nbr, const float* __restrict__ b_nbr,
    const float* __restrict__ b_n1,
    float* __restrict__ h, unsigned short* __restrict__ ub, int N)
{
    __shared__ float sW1[128 * 32];   // [k][c] natural layout, 16 KB
    __shared__ float sW2[32 * 32];    // [k][c], 4 KB
    __shared__ float sb1[32], sb2[32];

    const int tid = threadIdx.x;
    for (int i = tid; i < 128 * 32; i += 128) sW1[i] = W_in[i];
    for (int i = tid; i < 32 * 32; i += 128) sW2[i] = W_nbr[i];
    if (tid < 32) { sb1[tid] = b_in[tid]; sb2[tid] = b_nbr[tid] + b_n1[tid]; }
    __syncthreads();

    const int node = blockIdx.x * 128 + tid;
    if (node >= N) return;

    const float4* frow = (const float4*)(feat + (size_t)node * 128);

    float acc[32];
#pragma unroll
    for (int c = 0; c < 32; ++c) acc[c] = sb1[c];

    // GEMM1: per k, all lanes broadcast-read the same w row from LDS.
#pragma unroll 4
    for (int k4 = 0; k4 < 32; ++k4) {
        const float4 f = frow[k4];
        const float4* w0 = (const float4*)&sW1[(k4 * 4 + 0) * 32];
        const float4* w1 = (const float4*)&sW1[(k4 * 4 + 1) * 32];
        const float4* w2 = (const float4*)&sW1[(k4 * 4 + 2) * 32];
        const float4* w3 = (const float4*)&sW1[(k4 * 4 + 3) * 32];
#pragma unroll
        for (int c4 = 0; c4 < 8; ++c4) {
            float4 a0 = w0[c4], a1 = w1[c4], a2 = w2[c4], a3 = w3[c4];
            acc[c4 * 4 + 0] = fmaf(f.w, a3.x, fmaf(f.z, a2.x, fmaf(f.y, a1.x, fmaf(f.x, a0.x, acc[c4 * 4 + 0]))));
            acc[c4 * 4 + 1] = fmaf(f.w, a3.y, fmaf(f.z, a2.y, fmaf(f.y, a1.y, fmaf(f.x, a0.y, acc[c4 * 4 + 1]))));
            acc[c4 * 4 + 2] = fmaf(f.w, a3.z, fmaf(f.z, a2.z, fmaf(f.y, a1.z, fmaf(f.x, a0.z, acc[c4 * 4 + 2]))));
            acc[c4 * 4 + 3] = fmaf(f.w, a3.w, fmaf(f.z, a2.w, fmaf(f.y, a1.w, fmaf(f.x, a0.w, acc[c4 * 4 + 3]))));
        }
    }

    // store h row
    {
        float4* hrow = (float4*)(h + (size_t)node * 32);
#pragma unroll
        for (int c4 = 0; c4 < 8; ++c4)
            hrow[c4] = make_float4(acc[c4 * 4 + 0], acc[c4 * 4 + 1],
                                   acc[c4 * 4 + 2], acc[c4 * 4 + 3]);
    }

    // GEMM2 on register-resident h
    float acc2[32];
#pragma unroll
    for (int c = 0; c < 32; ++c) acc2[c] = sb2[c];
#pragma unroll
    for (int k = 0; k < 32; ++k) {
        const float hv = acc[k];
        const float4* wr = (const float4*)&sW2[k * 32];
#pragma unroll
        for (int c4 = 0; c4 < 8; ++c4) {
            float4 w = wr[c4];
            acc2[c4 * 4 + 0] = fmaf(hv, w.x, acc2[c4 * 4 + 0]);
            acc2[c4 * 4 + 1] = fmaf(hv, w.y, acc2[c4 * 4 + 1]);
            acc2[c4 * 4 + 2] = fmaf(hv, w.z, acc2[c4 * 4 + 2]);
            acc2[c4 * 4 + 3] = fmaf(hv, w.w, acc2[c4 * 4 + 3]);
        }
    }

    // sigmoid -> bf16 (RNE) -> channel-split tables, packed uint writes
    unsigned* ub32 = (unsigned*)ub;
#pragma unroll
    for (int j = 0; j < 16; ++j) {
        const int q = j >> 3, jj = j & 7;
        const int c = q * 16 + 2 * jj;
        float s0 = 1.0f / (1.0f + __expf(-acc2[c]));
        float s1 = 1.0f / (1.0f + __expf(-acc2[c + 1]));
        unsigned b0 = __float_as_uint(s0);
        b0 += 0x7FFFu + ((b0 >> 16) & 1u);
        unsigned b1 = __float_as_uint(s1);
        b1 += 0x7FFFu + ((b1 >> 16) & 1u);
        ub32[((size_t)q * N + node) * 8 + jj] = (b0 >> 16) | (b1 & 0xFFFF0000u);
    }
}

// ---------------------------------------------------------------------------
// Per-bucket segment max in LDS, split 2 ways by channel half (q=blockIdx.y).
// Pair codes staged in LDS tiles (coalesced); 8-lane groups, each lane
// gathers a u32 (2 bf16 channels); 8 pairs in flight per lane.
// ---------------------------------------------------------------------------
__global__ __launch_bounds__(256) void bucket_max(
    const unsigned* __restrict__ pairs_g, const int* __restrict__ gbase,
    const int* __restrict__ gtotal, const unsigned* __restrict__ ub32,
    float* __restrict__ agg, int N)
{
    __shared__ unsigned aggL[BSZ * CPG];   // 16 KB
    __shared__ int degL[BSZ];              // 1 KB
    __shared__ unsigned tile[TS];          // 8 KB

    const int tid = threadIdx.x;
    const int b = blockIdx.x;
    const int q = blockIdx.y;              // channel half
    const int v0 = b * BSZ;
    const unsigned* ut = ub32 + (size_t)q * N * 8;  // 8 u32 per node

    for (int i = tid; i < BSZ * CPG; i += 256) aggL[i] = 0u;
    for (int i = tid; i < BSZ; i += 256) degL[i] = 0;
    __syncthreads();

    const int start = gbase[b];
    const int cnt = gtotal[b];
    const int gg = tid >> 3;       // 32 groups of 8 lanes
    const int cl = tid & 7;

    for (int t0 = 0; t0 < cnt; t0 += TS) {
        const int tn = min(TS, cnt - t0);
        for (int i = tid; i < tn; i += 256) tile[i] = pairs_g[start + t0 + i];
        __syncthreads();

        // group gg owns pairs p = gg + 32*k, k in [0, kmax)
        const int kmax = (tn - gg + 31) >> 5;   // <=0 if gg >= tn
        for (int kk = 0; kk < kmax; kk += 8) {
            unsigned c0, c1, c2, c3, c4, c5, c6, c7;
            const int pb = (kk << 5) + gg;
            const int pm = tn - 1;
            c0 = tile[min(pb + 0 * 32, pm)];
            c1 = tile[min(pb + 1 * 32, pm)];
            c2 = tile[min(pb + 2 * 32, pm)];
            c3 = tile[min(pb + 3 * 32, pm)];
            c4 = tile[min(pb + 4 * 32, pm)];
            c5 = tile[min(pb + 5 * 32, pm)];
            c6 = tile[min(pb + 6 * 32, pm)];
            c7 = tile[min(pb + 7 * 32, pm)];
            unsigned x0 = ut[(size_t)(c0 & 0x1FFFF) * 8 + cl];
            unsigned x1 = ut[(size_t)(c1 & 0x1FFFF) * 8 + cl];
            unsigned x2 = ut[(size_t)(c2 & 0x1FFFF) * 8 + cl];
            unsigned x3 = ut[(size_t)(c3 & 0x1FFFF) * 8 + cl];
            unsigned x4 = ut[(size_t)(c4 & 0x1FFFF) * 8 + cl];
            unsigned x5 = ut[(size_t)(c5 & 0x1FFFF) * 8 + cl];
            unsigned x6 = ut[(size_t)(c6 & 0x1FFFF) * 8 + cl];
            unsigned x7 = ut[(size_t)(c7 & 0x1FFFF) * 8 + cl];
            // duplicate (clamped) pairs are idempotent under max
            atomicMax(&aggL[(c0 >> 17) * CPG + 2 * cl], (x0 & 0xFFFFu) << 16);
            atomicMax(&aggL[(c0 >> 17) * CPG + 2 * cl + 1], x0 & 0xFFFF0000u);
            atomicMax(&aggL[(c1 >> 17) * CPG + 2 * cl], (x1 & 0xFFFFu) << 16);
            atomicMax(&aggL[(c1 >> 17) * CPG + 2 * cl + 1], x1 & 0xFFFF0000u);
            atomicMax(&aggL[(c2 >> 17) * CPG + 2 * cl], (x2 & 0xFFFFu) << 16);
            atomicMax(&aggL[(c2 >> 17) * CPG + 2 * cl + 1], x2 & 0xFFFF0000u);
            atomicMax(&aggL[(c3 >> 17) * CPG + 2 * cl], (x3 & 0xFFFFu) << 16);
            atomicMax(&aggL[(c3 >> 17) * CPG + 2 * cl + 1], x3 & 0xFFFF0000u);
            atomicMax(&aggL[(c4 >> 17) * CPG + 2 * cl], (x4 & 0xFFFFu) << 16);
            atomicMax(&aggL[(c4 >> 17) * CPG + 2 * cl + 1], x4 & 0xFFFF0000u);
            atomicMax(&aggL[(c5 >> 17) * CPG + 2 * cl], (x5 & 0xFFFFu) << 16);
            atomicMax(&aggL[(c5 >> 17) * CPG + 2 * cl + 1], x5 & 0xFFFF0000u);
            atomicMax(&aggL[(c6 >> 17) * CPG + 2 * cl], (x6 & 0xFFFFu) << 16);
            atomicMax(&aggL[(c6 >> 17) * CPG + 2 * cl + 1], x6 & 0xFFFF0000u);
            atomicMax(&aggL[(c7 >> 17) * CPG + 2 * cl], (x7 & 0xFFFFu) << 16);
            atomicMax(&aggL[(c7 >> 17) * CPG + 2 * cl + 1], x7 & 0xFFFF0000u);
            if (cl == 0) {
                if (pb + 0 * 32 < tn) atomicAdd(&degL[c0 >> 17], 1);
                if (pb + 1 * 32 < tn) atomicAdd(&degL[c1 >> 17], 1);
                if (pb + 2 * 32 < tn) atomicAdd(&degL[c2 >> 17], 1);
                if (pb + 3 * 32 < tn) atomicAdd(&degL[c3 >> 17], 1);
                if (pb + 4 * 32 < tn) atomicAdd(&degL[c4 >> 17], 1);
                if (pb + 5 * 32 < tn) atomicAdd(&degL[c5 >> 17], 1);
                if (pb + 6 * 32 < tn) atomicAdd(&degL[c6 >> 17], 1);
                if (pb + 7 * 32 < tn) atomicAdd(&degL[c7 >> 17], 1);
            }
        }
        __syncthreads();
    }

    for (int i = tid; i < BSZ * CPG; i += 256) {
        int vl = i >> 4;
        int v = v0 + vl;
        if (v < N) {
            float val = (degL[vl] > 1) ? __uint_as_float(aggL[i]) : 0.f;
            agg[(size_t)v * DH + q * CPG + (i & 15)] = val;
        }
    }
}

// ---------------------------------------------------------------------------
// One THREAD per node: out = concat(h, agg) @ W_ffnn + b_ffnn.
// ---------------------------------------------------------------------------
__global__ __launch_bounds__(128) void finalize(
    const float* __restrict__ h, const float* __restrict__ agg,
    const float* __restrict__ W_ffnn, const float* __restrict__ b_ffnn,
    float* __restrict__ out, int N)
{
    __shared__ float sW[64 * 32];   // [k][c] natural layout, 8 KB
    __shared__ float sb[32];

    const int tid = threadIdx.x;
    for (int i = tid; i < 64 * 32; i += 128) sW[i] = W_ffnn[i];
    if (tid < 32) sb[tid] = b_ffnn[tid];
    __syncthreads();

    const int node = blockIdx.x * 128 + tid;
    if (node >= N) return;

    const float4* hrow = (const float4*)(h + (size_t)node * 32);
    const float4* arow = (const float4*)(agg + (size_t)node * 32);

    float acc[32];
#pragma unroll
    for (int c = 0; c < 32; ++c) acc[c] = sb[c];

#pragma unroll 2
    for (int k4 = 0; k4 < 8; ++k4) {
        const float4 f = hrow[k4];
        const float4* w0 = (const float4*)&sW[(k4 * 4 + 0) * 32];
        const float4* w1 = (const float4*)&sW[(k4 * 4 + 1) * 32];
        const float4* w2 = (const float4*)&sW[(k4 * 4 + 2) * 32];
        const float4* w3 = (const float4*)&sW[(k4 * 4 + 3) * 32];
#pragma unroll
        for (int c4 = 0; c4 < 8; ++c4) {
            float4 a0 = w0[c4], a1 = w1[c4], a2 = w2[c4], a3 = w3[c4];
            acc[c4 * 4 + 0] = fmaf(f.w, a3.x, fmaf(f.z, a2.x, fmaf(f.y, a1.x, fmaf(f.x, a0.x, acc[c4 * 4 + 0]))));
            acc[c4 * 4 + 1] = fmaf(f.w, a3.y, fmaf(f.z, a2.y, fmaf(f.y, a1.y, fmaf(f.x, a0.y, acc[c4 * 4 + 1]))));
            acc[c4 * 4 + 2] = fmaf(f.w, a3.z, fmaf(f.z, a2.z, fmaf(f.y, a1.z, fmaf(f.x, a0.z, acc[c4 * 4 + 2]))));
            acc[c4 * 4 + 3] = fmaf(f.w, a3.w, fmaf(f.z, a2.w, fmaf(f.y, a1.w, fmaf(f.x, a0.w, acc[c4 * 4 + 3]))));
        }
    }
#pragma unroll 2
    for (int k4 = 0; k4 < 8; ++k4) {
        const float4 f = arow[k4];
        const float4* w0 = (const float4*)&sW[(32 + k4 * 4 + 0) * 32];
        const float4* w1 = (const float4*)&sW[(32 + k4 * 4 + 1) * 32];
        const float4* w2 = (const float4*)&sW[(32 + k4 * 4 + 2) * 32];
        const float4* w3 = (const float4*)&sW[(32 + k4 * 4 + 3) * 32];
#pragma unroll
        for (int c4 = 0; c4 < 8; ++c4) {
            float4 a0 = w0[c4], a1 = w1[c4], a2 = w2[c4], a3 = w3[c4];
            acc[c4 * 4 + 0] = fmaf(f.w, a3.x, fmaf(f.z, a2.x, fmaf(f.y, a1.x, fmaf(f.x, a0.x, acc[c4 * 4 + 0]))));
            acc[c4 * 4 + 1] = fmaf(f.w, a3.y, fmaf(f.z, a2.y, fmaf(f.y, a1.y, fmaf(f.x, a0.y, acc[c4 * 4 + 1]))));
            acc[c4 * 4 + 2] = fmaf(f.w, a3.z, fmaf(f.z, a2.z, fmaf(f.y, a1.z, fmaf(f.x, a0.z, acc[c4 * 4 + 2]))));
            acc[c4 * 4 + 3] = fmaf(f.w, a3.w, fmaf(f.z, a2.w, fmaf(f.y, a1.w, fmaf(f.x, a0.w, acc[c4 * 4 + 3]))));
        }
    }

    float4* orow = (float4*)(out + (size_t)node * 32);
#pragma unroll
    for (int c4 = 0; c4 < 8; ++c4)
        orow[c4] = make_float4(acc[c4 * 4 + 0], acc[c4 * 4 + 1],
                               acc[c4 * 4 + 2], acc[c4 * 4 + 3]);
}

// ---------------------------------------------------------------------------
extern "C" void kernel_launch(void* const* d_in, const int* in_sizes, int n_in,
                              void* d_out, int out_size, void* d_ws, size_t ws_size,
                              hipStream_t stream)
{
    const float* feat   = (const float*)d_in[0];
    const int*   src    = (const int*)d_in[1];
    const int*   dst    = (const int*)d_in[2];
    const float* W_in   = (const float*)d_in[3];
    const float* b_in   = (const float*)d_in[4];
    const float* W_nbr  = (const float*)d_in[5];
    const float* b_nbr  = (const float*)d_in[6];
    const float* b_n1   = (const float*)d_in[7];
    const float* W_ffnn = (const float*)d_in[8];
    const float* b_ffnn = (const float*)d_in[9];
    float* out = (float*)d_out;

    const int N = in_sizes[0] / 128;   // 100000 (N <= 131072 required by packing)
    const int E = in_sizes[1];
    const int B = (N + BSZ - 1) / BSZ; // 391 buckets (<= NBP)

    // u (bf16, channel-split, 6.4MB) aliases d_out (12.8MB): written by
    // node_proj, consumed by bucket_max, then finalize overwrites out.
    unsigned short* ub = (unsigned short*)out;
    float* h       = (float*)d_ws;                  // N*32 f32
    float* agg     = h + (size_t)N * DH;            // N*32 f32
    int*   gtotal  = (int*)(agg + (size_t)N * DH);  // NBP
    int*   gbase   = gtotal + NBP;                  // NBP
    int*   gcursor = gbase + NBP;                   // NBP
    unsigned* pairs_g = (unsigned*)(gcursor + NBP); // 2E u32

    const int egrid = (E + SCAT_E - 1) / SCAT_E;

    zero_counts<<<(NBP + 255) / 256, 256, 0, stream>>>(gtotal);
    precount<<<egrid, 256, 0, stream>>>(src, dst, gtotal, E);
    scan_buckets<<<1, 256, 0, stream>>>(gtotal, gbase, gcursor);
    bucket_scatter<<<egrid, 256, 0, stream>>>(src, dst, gcursor, pairs_g, E, B);
    node_proj<<<(N + 127) / 128, 128, 0, stream>>>(feat, W_in, b_in, W_nbr, b_nbr,
                                                   b_n1, h, ub, N);
    dim3 gmax(B, NSPLIT);
    bucket_max<<<gmax, 256, 0, stream>>>(pairs_g, gbase, gtotal, (const unsigned*)ub,
                                         agg, N);
    finalize<<<(N + 127) / 128, 128, 0, stream>>>(h, agg, W_ffnn, b_ffnn, out, N);
}